// Round 6
// baseline (256.413 us; speedup 1.0000x reference)
//
#include <hip/hip_runtime.h>
#include <math.h>

#define H_   768
#define NH_  4
#define HD_  192
#define E_   9
#define R_   12
#define D_   64
#define B_   4
#define S_   1024
#define H3_  (3 * H_)
#define MBS_ (B_ * S_)

typedef unsigned short u16;
typedef __attribute__((ext_vector_type(4))) int   i32x4;
typedef __attribute__((ext_vector_type(4))) float f32x4;
typedef __attribute__((ext_vector_type(8))) unsigned short u16x8;

static const long OUT_REL_OFF = (long)B_ * E_ * S_ * S_;                    // 37,748,736
static const long OUT_ENH_OFF = OUT_REL_OFF + (long)B_ * R_ * S_ * S_;      // 88,080,384

__device__ __forceinline__ u16 f2bf(float f) {
    unsigned u = __builtin_bit_cast(unsigned, f);
    return (u16)((u + 0x7fffu + ((u >> 16) & 1u)) >> 16);
}
__device__ __forceinline__ float bf2f(u16 h) {
    return __builtin_bit_cast(float, (unsigned)h << 16);
}
__device__ __forceinline__ void gload16(const u16* g, u16* l) {
    __builtin_amdgcn_global_load_lds(
        (__attribute__((address_space(1))) void*)g,
        (__attribute__((address_space(3))) void*)l, 16, 0, 0);
}
__device__ __forceinline__ void mfma_bf16(f32x4& acc, i32x4 a, i32x4 b) {
    asm volatile("v_mfma_f32_16x16x32_bf16 %0, %1, %2, %0"
                 : "+v"(acc) : "v"(a), "v"(b));
}

// ---------------------------------------------------------------------------
// bf16 MFMA GEMM, NT: C[m,n] = sum_k A[m,k]*B[n,k]. BMxBN tile, BK=64,
// 4 waves (2x2), 16x16x32 MFMA. LDS XOR-swizzled (granule ^= row&7) with
// pre-swizzled global source. XCD-swizzled grid. NS=2: double-buffered LDS,
// prefetch tile t+1 before computing tile t, ONE barrier per K-step
// (vmcnt drain lands after MFMA -> load latency hidden under compute).
// NS=1 only valid for K==64 (single K-step: logits GEMMs).
// EPI 0: +bias (OBF sel bf16/fp32 out)
// EPI 1: logits epilogue (mask/tril/*0.125), fp32 out
// EPI 3: EPI1 + per-row max partials -> aux[(z*S+gm)*16 + bx*2+wc]
// EPI 4: +bias then fused interleaved RoPE (pair via shfl_xor 1), bf16 out
// EPI 5: t=exp(v*scale) (0 if masked), bf16 out + row-sum partials -> aux
// EPI 6: v *= 1/rowsum (aux = psum in), bf16 out
// ---------------------------------------------------------------------------
template<int BM, int BN, int EPI, int OBF, int NS>
__global__ __launch_bounds__(256) void gemm_mfma(
    const u16* __restrict__ A, const u16* __restrict__ Bw,
    const float* __restrict__ bias, void* __restrict__ Cv,
    int K, int lda, int ldb, int ldc, int nh,
    long sAb, long sAh, long sBb, long sBh, long sCb, long sCh,
    const float* __restrict__ mask, float scale, float* __restrict__ aux)
{
    constexpr int MI = BM / 32, NJ = BN / 32;
    constexpr int BUFE = (BM + BN) * 64;            // u16 elems per stage buffer
    const int z = blockIdx.z;
    const int zb = z / nh, zh = z - zb * nh;
    A  += zb * sAb + zh * sAh;
    Bw += zb * sBb + zh * sBh;

    // XCD-aware bijective swizzle of (bx,by); all grids have nwg%8==0
    const int gx = gridDim.x, gy = gridDim.y;
    int id = blockIdx.y * gx + blockIdx.x;
    const int nwg = gx * gy;
    if ((nwg & 7) == 0) id = (id & 7) * (nwg >> 3) + (id >> 3);
    const int bx = id % gx, by = id / gx;
    const int m0 = by * BM, n0 = bx * BN;

    __shared__ u16 lds[NS * BUFE];

    const int t = threadIdx.x;
    const int lane = t & 63, wid = t >> 6;
    const int wr = wid >> 1, wc = wid & 1;
    const int l16 = lane & 15, l4 = lane >> 4;

    auto stage = [&](int kt, int buf) {
        u16* la = lds + buf * BUFE;
        u16* lb = la + BM * 64;
        const int k0 = kt << 6;
        #pragma unroll
        for (int i = 0; i < BM / 32; ++i) {
            const int e = i * 256 + t;
            const int row = e >> 3;
            const int c = ((e & 7) ^ (row & 7)) << 3;      // pre-swizzled source
            gload16(A + (long)(m0 + row) * lda + k0 + c, la + e * 8);
        }
        #pragma unroll
        for (int i = 0; i < BN / 32; ++i) {
            const int e = i * 256 + t;
            const int row = e >> 3;
            const int c = ((e & 7) ^ (row & 7)) << 3;
            gload16(Bw + (long)(n0 + row) * ldb + k0 + c, lb + e * 8);
        }
    };

    f32x4 acc[MI][NJ];
    #pragma unroll
    for (int mi = 0; mi < MI; ++mi)
        #pragma unroll
        for (int nj = 0; nj < NJ; ++nj)
            #pragma unroll
            for (int q = 0; q < 4; ++q) acc[mi][nj][q] = 0.0f;

    const int nt = K >> 6;
    stage(0, 0);
    __syncthreads();
    for (int tt = 0; tt < nt; ++tt) {
        const int cur = (NS == 2) ? (tt & 1) : 0;
        if (NS == 2 && tt + 1 < nt) stage(tt + 1, cur ^ 1);
        const u16* la = lds + cur * BUFE;
        const u16* lb = la + BM * 64;
        i32x4 af[MI][2], bfr[NJ][2];
        #pragma unroll
        for (int mi = 0; mi < MI; ++mi)
            #pragma unroll
            for (int kk = 0; kk < 2; ++kk) {
                const int row = wr * (BM / 2) + mi * 16 + l16;
                af[mi][kk] = *(const i32x4*)&la[row * 64 + ((((kk << 2) + l4) ^ (row & 7)) << 3)];
            }
        #pragma unroll
        for (int nj = 0; nj < NJ; ++nj)
            #pragma unroll
            for (int kk = 0; kk < 2; ++kk) {
                const int row = wc * (BN / 2) + nj * 16 + l16;
                bfr[nj][kk] = *(const i32x4*)&lb[row * 64 + ((((kk << 2) + l4) ^ (row & 7)) << 3)];
            }
        #pragma unroll
        for (int kk = 0; kk < 2; ++kk)
            #pragma unroll
            for (int mi = 0; mi < MI; ++mi)
                #pragma unroll
                for (int nj = 0; nj < NJ; ++nj)
                    mfma_bf16(acc[mi][nj], af[mi][kk], bfr[nj][kk]);
        __syncthreads();   // drains vmcnt (t+1 prefetch) AFTER this tile's MFMAs
    }
    __builtin_amdgcn_sched_barrier(0);
    asm volatile("s_nop 7");
    asm volatile("s_nop 7");
    __builtin_amdgcn_sched_barrier(0);

    if (EPI == 1 || EPI == 3 || EPI == 5) mask += (long)zb * S_;
    const long cbase = zb * sCb + zh * sCh;

    float* sminv = (float*)lds;   // EPI 6 only: reuse dead LDS after K-loop
    if (EPI == 6) {               // preload 1/rowsum from 16 partials per row
        if (t < BM) {
            const float* pp = aux + ((long)z * S_ + m0 + t) * 16;
            float s = 0.0f;
            #pragma unroll
            for (int i = 0; i < 16; ++i) s += pp[i];
            sminv[t] = 1.0f / s;
        }
        __syncthreads();
    }

    float red[MI][4];
    if (EPI == 3 || EPI == 5) {
        #pragma unroll
        for (int mi = 0; mi < MI; ++mi)
            #pragma unroll
            for (int r = 0; r < 4; ++r) red[mi][r] = (EPI == 3) ? -INFINITY : 0.0f;
    }

    #pragma unroll
    for (int mi = 0; mi < MI; ++mi) {
        #pragma unroll
        for (int nj = 0; nj < NJ; ++nj) {
            const int gn = n0 + wc * (BN / 2) + nj * 16 + l16;
            const float bv = ((EPI == 0 || EPI == 4) && bias) ? bias[gn] : 0.0f;
            float invf = 0.0f;
            if (EPI == 4) invf = exp2f(-(float)((gn & 63) >> 1) * 0.41524101186092503f);
            #pragma unroll
            for (int r = 0; r < 4; ++r) {
                const int gm = m0 + wr * (BM / 2) + mi * 16 + l4 * 4 + r;
                float v = acc[mi][nj][r];
                const long cidx = cbase + (long)gm * ldc + gn;
                if (EPI == 0) {
                    v += bv;
                    if (OBF) ((u16*)Cv)[cidx] = f2bf(v);
                    else     ((float*)Cv)[cidx] = v;
                } else if (EPI == 1 || EPI == 3) {
                    const float pad = mask[gn];
                    v = v * pad - (1.0f - pad) * 1e12f;
                    if (gm > gn) v -= 1e12f;
                    v *= 0.125f;
                    ((float*)Cv)[cidx] = v;
                    if (EPI == 3) red[mi][r] = fmaxf(red[mi][r], v);
                } else if (EPI == 5) {
                    float tv = 0.0f;
                    if (mask[gn] != 0.0f) tv = __expf(v * scale);
                    ((u16*)Cv)[cidx] = f2bf(tv);
                    red[mi][r] += tv;
                } else if (EPI == 6) {
                    v *= sminv[gm - m0];
                    ((u16*)Cv)[cidx] = f2bf(v);
                } else { // EPI == 4
                    v += bv;
                    const int sp = gm & (S_ - 1);
                    float sn, cs;
                    __sincosf((float)sp * invf, &sn, &cs);
                    const float pv = __shfl_xor(v, 1, 64);
                    v = (gn & 1) ? fmaf(v, cs, pv * sn) : fmaf(v, cs, -pv * sn);
                    ((u16*)Cv)[cidx] = f2bf(v);
                }
            }
        }
    }

    if (EPI == 3 || EPI == 5) {
        #pragma unroll
        for (int mi = 0; mi < MI; ++mi) {
            #pragma unroll
            for (int r = 0; r < 4; ++r) {
                float m = red[mi][r];
                if (EPI == 3) {
                    m = fmaxf(m, __shfl_xor(m, 1, 64));
                    m = fmaxf(m, __shfl_xor(m, 2, 64));
                    m = fmaxf(m, __shfl_xor(m, 4, 64));
                    m = fmaxf(m, __shfl_xor(m, 8, 64));
                } else {
                    m += __shfl_xor(m, 1, 64);
                    m += __shfl_xor(m, 2, 64);
                    m += __shfl_xor(m, 4, 64);
                    m += __shfl_xor(m, 8, 64);
                }
                if (l16 == 0) {
                    const int gm = m0 + wr * (BM / 2) + mi * 16 + l4 * 4 + r;
                    aux[((long)z * S_ + gm) * 16 + bx * 2 + wc] = m;
                }
            }
        }
    }
}

// ---------------------------------------------------------------------------
// Fused fp32->bf16 cast of hs + 5 weight matrices. 1024 elems per block.
// ---------------------------------------------------------------------------
__global__ __launch_bounds__(256) void cast_all(
    const float* __restrict__ hs, const float* __restrict__ ipw,
    const float* __restrict__ opw, const float* __restrict__ gw,
    const float* __restrict__ entw, const float* __restrict__ relw,
    u16* hs_o, u16* ipw_o, u16* opw_o, u16* gw_o, u16* entw_o, u16* relw_o)
{
    const int blk = blockIdx.x;
    const float* in; u16* out; long base;
    if      (blk < 3072) { in = hs;   out = hs_o;   base = (long)blk * 1024; }
    else if (blk < 4800) { in = ipw;  out = ipw_o;  base = (long)(blk - 3072) * 1024; }
    else if (blk < 5376) { in = opw;  out = opw_o;  base = (long)(blk - 4800) * 1024; }
    else if (blk < 5952) { in = gw;   out = gw_o;   base = (long)(blk - 5376) * 1024; }
    else if (blk < 6816) { in = entw; out = entw_o; base = (long)(blk - 5952) * 1024; }
    else                 { in = relw; out = relw_o; base = (long)(blk - 6816) * 1024; }
    const long idx = base + (long)threadIdx.x * 4;
    const float4 v = *(const float4*)&in[idx];
    ushort4 o; o.x = f2bf(v.x); o.y = f2bf(v.y); o.z = f2bf(v.z); o.w = f2bf(v.w);
    *(ushort4*)&out[idx] = o;
}

// ---------------------------------------------------------------------------
// V transpose: vt[(b,h)][d][s] = qkv_bf[(b,s)][1536 + h*192 + d]
// ---------------------------------------------------------------------------
__global__ __launch_bounds__(256) void transpose_v(
    const u16* __restrict__ qkv, u16* __restrict__ vt)
{
    __shared__ u16 tile[64][72];
    const int z = blockIdx.z, b = z >> 2, h = z & 3;
    const int d0 = blockIdx.x * 64, s0 = blockIdx.y * 64;
    const int t = threadIdx.x;
    const int r = t >> 2, c = (t & 3) << 4;
    const u16* src = qkv + ((long)(b * S_ + s0 + r)) * H3_ + 2 * H_ + h * HD_ + d0 + c;
    *(u16x8*)&tile[r][c]     = *(const u16x8*)src;
    *(u16x8*)&tile[r][c + 8] = *(const u16x8*)(src + 8);
    __syncthreads();
    u16 tmp[16];
    #pragma unroll
    for (int i = 0; i < 16; ++i) tmp[i] = tile[c + i][r];
    u16* dst = vt + ((long)z * HD_ + d0 + r) * S_ + s0 + c;
    *(u16x8*)dst       = *(u16x8*)&tmp[0];
    *(u16x8*)(dst + 8) = *(u16x8*)&tmp[8];
}

// ---------------------------------------------------------------------------
// x = hs + sigmoid(gl)*ao ; LayerNorm -> enh fp32 (d_out) + relh[:768] bf16
// ao/gl packed in aogl rows of 1536: [0..768) = ao, [768..1536) = gl.
// ---------------------------------------------------------------------------
__global__ __launch_bounds__(256) void gate_ln_bf(
    const float* __restrict__ hs, const u16* __restrict__ aogl,
    const float* __restrict__ g, const float* __restrict__ bta,
    float* __restrict__ enh, u16* __restrict__ relh)
{
    const long row = blockIdx.x;
    const float* hrow = hs + row * H_;
    const u16* arow = aogl + row * (2 * H_);
    const int tid = threadIdx.x;
    float x[3];
    float sum = 0.0f, sq = 0.0f;
    #pragma unroll
    for (int i = 0; i < 3; ++i) {
        const int j = tid + i * 256;
        const float a = bf2f(arow[j]);
        const float gt = 1.0f / (1.0f + __expf(-bf2f(arow[H_ + j])));
        const float xv = hrow[j] + gt * a;
        x[i] = xv; sum += xv; sq += xv * xv;
    }
    __shared__ float sm[8];
    #pragma unroll
    for (int o = 32; o > 0; o >>= 1) {
        sum += __shfl_xor(sum, o, 64);
        sq  += __shfl_xor(sq, o, 64);
    }
    const int lane = tid & 63, wid = tid >> 6;
    if (lane == 0) { sm[wid] = sum; sm[4 + wid] = sq; }
    __syncthreads();
    sum = sm[0] + sm[1] + sm[2] + sm[3];
    sq  = sm[4] + sm[5] + sm[6] + sm[7];
    const float mu = sum * (1.0f / (float)H_);
    float var = sq * (1.0f / (float)H_) - mu * mu;
    var = fmaxf(var, 0.0f);
    const float inv = 1.0f / sqrtf(var + 1e-5f);
    #pragma unroll
    for (int i = 0; i < 3; ++i) {
        const int j = tid + i * 256;
        const float o = (x[i] - mu) * inv * g[j] + bta[j];
        enh[row * H_ + j] = o;
        relh[row * (2 * H_) + j] = f2bf(o);
    }
}

// ---------------------------------------------------------------------------
// Fused: prior[t] = max over 16 partials; relh[:,768:] = relu(prior@pw^T+pb)
// One block per (b,m) row.
// ---------------------------------------------------------------------------
__global__ __launch_bounds__(256) void prior_fused(
    const float* __restrict__ pmax, const float* __restrict__ pw,
    const float* __restrict__ pb, u16* __restrict__ relh)
{
    const int row = blockIdx.x;               // b*S + m
    const int b = row >> 10, m = row & (S_ - 1);
    __shared__ float pr[E_];
    const int tid = threadIdx.x;
    if (tid < E_) {
        const float* pp = pmax + ((long)(b * E_ + tid) * S_ + m) * 16;
        float mx = -INFINITY;
        #pragma unroll
        for (int i = 0; i < 16; ++i) mx = fmaxf(mx, pp[i]);
        pr[tid] = mx;
    }
    __syncthreads();
    float p[E_];
    #pragma unroll
    for (int e = 0; e < E_; ++e) p[e] = pr[e];
    u16* orow = relh + (long)row * (2 * H_) + H_;
    #pragma unroll
    for (int i = 0; i < 3; ++i) {
        const int j = tid + i * 256;
        float a = pb[j];
        #pragma unroll
        for (int e = 0; e < E_; ++e) a = fmaf(p[e], pw[j * E_ + e], a);
        orow[j] = f2bf(fmaxf(a, 0.0f));
    }
}

// ---------------------------------------------------------------------------
extern "C" void kernel_launch(void* const* d_in, const int* in_sizes, int n_in,
                              void* d_out, int out_size, void* d_ws, size_t ws_size,
                              hipStream_t stream)
{
    const float* hs   = (const float*)d_in[0];
    const float* mask = (const float*)d_in[1];
    const float* ipw  = (const float*)d_in[2];
    const float* ipb  = (const float*)d_in[3];
    const float* opw  = (const float*)d_in[4];
    const float* opb  = (const float*)d_in[5];
    const float* gw   = (const float*)d_in[6];
    const float* gb   = (const float*)d_in[7];
    const float* lng  = (const float*)d_in[8];
    const float* lnb  = (const float*)d_in[9];
    const float* entw = (const float*)d_in[10];
    const float* entb = (const float*)d_in[11];
    const float* prw  = (const float*)d_in[12];
    const float* prb  = (const float*)d_in[13];
    const float* relw = (const float*)d_in[14];
    const float* relb = (const float*)d_in[15];
    float* out = (float*)d_out;
    char* base = (char*)d_ws;

    // ws layout (bytes)
    u16* ipw_bf  = (u16*)(base + 0);          // 3,538,944
    u16* opw_bf  = (u16*)(base + 3538944);    // 1,179,648  } contiguous pair ->
    u16* gw_bf   = (u16*)(base + 4718592);    // 1,179,648  } combined [1536][768]
    u16* entw_bf = (u16*)(base + 5898240);    // 1,769,472
    u16* relw_bf = (u16*)(base + 7667712);    // 4,718,592
    u16* hs_bf   = (u16*)(base + 12386304);   // 6,291,456  [dead after qkv]
    u16* qkv_bf  = (u16*)(base + 18677760);   // 18,874,368 [dead after scores]
    u16* vt_bf   = (u16*)(base + 37552128);   // 6,291,456  [dead after PV]
    u16* sc_bf   = (u16*)(base + 43843584);   // 33,554,432 [dead after PV]
    u16* ctx_bf  = (u16*)(base + 77398016);   // 6,291,456
    u16* aogl_bf = (u16*)(base + 83689472);   // 12,582,912
    float* bias2 = (float*)(base + 96272384); //      6,144 (opb|gb)
    float* psum  = (float*)(base + 96280576); //  1,048,576
    float* pmax  = (float*)(base + 97329152); //  2,359,296
    u16* relh_bf = (u16*)(base + 18677760);   // 12,582,912 (reuse qkv region)
    u16* projr   = (u16*)(base + 37552128);   // 12,582,912 (reuse vt+sc region)
    float* enh   = out + OUT_ENH_OFF;

    const float qscale = 0.07216878364870323f; // 1/sqrt(192)

    // combined out_proj|gate bias
    hipMemcpyAsync(bias2, opb, H_ * sizeof(float), hipMemcpyDeviceToDevice, stream);
    hipMemcpyAsync(bias2 + H_, gb, H_ * sizeof(float), hipMemcpyDeviceToDevice, stream);

    // 0. casts
    cast_all<<<9120, 256, 0, stream>>>(hs, ipw, opw, gw, entw, relw,
                                       hs_bf, ipw_bf, opw_bf, gw_bf, entw_bf, relw_bf);

    // 1. qkv = hs @ in_proj_w.T + b   (4096 x 2304, K=768)
    gemm_mfma<128,128,0,1,2><<<dim3(18, 32, 1), 256, 0, stream>>>(
        hs_bf, ipw_bf, ipb, qkv_bf, H_, H_, H_, H3_, 1,
        0,0,0,0,0,0, nullptr, 0.0f, nullptr);

    // 2. V transpose
    transpose_v<<<dim3(3, 16, 16), 256, 0, stream>>>(qkv_bf, vt_bf);

    // 3. scores: t = exp(QK^T/sqrt(HD)) (masked->0), bf16 + row-sum partials
    gemm_mfma<128,128,5,1,2><<<dim3(8, 8, B_ * NH_), 256, 0, stream>>>(
        qkv_bf, qkv_bf + H_, nullptr, sc_bf, HD_, H3_, H3_, S_, NH_,
        (long)S_ * H3_, HD_, (long)S_ * H3_, HD_,
        (long)NH_ * S_ * S_, (long)S_ * S_, mask, qscale, psum);

    // 4. ctx = (T @ V) / rowsum   (16 x 1024 x 192, K=1024)
    gemm_mfma<128,64,6,1,2><<<dim3(3, 8, B_ * NH_), 256, 0, stream>>>(
        sc_bf, vt_bf, nullptr, ctx_bf, S_, S_, S_, H_, NH_,
        (long)NH_ * S_ * S_, (long)S_ * S_, (long)NH_ * HD_ * S_, (long)HD_ * S_,
        (long)S_ * H_, HD_, nullptr, 0.0f, psum);

    // 5. [attn_out | gate_lin] = ctx @ [opw|gw]^T + [opb|gb]  (4096 x 1536, K=768)
    gemm_mfma<128,128,0,1,2><<<dim3(12, 32, 1), 256, 0, stream>>>(
        ctx_bf, opw_bf, bias2, aogl_bf, H_, H_, H_, 2 * H_, 1,
        0,0,0,0,0,0, nullptr, 0.0f, nullptr);

    // 6. enhanced = LN(hs + sigmoid(gl)*ao) -> enh fp32 + relh[:768]
    gate_ln_bf<<<MBS_, 256, 0, stream>>>(hs, aogl_bf, lng, lnb, enh, relh_bf);

    // 7. ent projection + fused RoPE (4096 x 1152, K=768) -> projr bf16
    gemm_mfma<128,128,4,1,2><<<dim3(9, 32, 1), 256, 0, stream>>>(
        relh_bf, entw_bf, entb, projr, H_, 2 * H_, H_, E_ * 2 * D_, 1,
        0,0,0,0,0,0, nullptr, 0.0f, nullptr);

    // 8. ent logits + fused rowmax partials -> out[0], pmax   (K=64, NS=1)
    gemm_mfma<128,128,3,0,1><<<dim3(8, 8, B_ * E_), 256, 0, stream>>>(
        projr, projr + D_, nullptr, out, D_, E_ * 2 * D_, E_ * 2 * D_, S_, E_,
        (long)S_ * E_ * 2 * D_, 2 * D_, (long)S_ * E_ * 2 * D_, 2 * D_,
        (long)E_ * S_ * S_, (long)S_ * S_, mask, 0.0f, pmax);

    // 9. prior reduce + feat -> relh[:, 768:]
    prior_fused<<<MBS_, 256, 0, stream>>>(pmax, prw, prb, relh_bf);

    // 10. rel projection + fused RoPE (4096 x 1536, K=1536) -> projr bf16
    gemm_mfma<128,128,4,1,2><<<dim3(12, 32, 1), 256, 0, stream>>>(
        relh_bf, relw_bf, relb, projr, 2 * H_, 2 * H_, 2 * H_, R_ * 2 * D_, 1,
        0,0,0,0,0,0, nullptr, 0.0f, nullptr);

    // 11. rel logits -> out[1]   (48 x 1024 x 1024, K=64, NS=1)
    gemm_mfma<128,128,1,0,1><<<dim3(8, 8, B_ * R_), 256, 0, stream>>>(
        projr, projr + D_, nullptr, out + OUT_REL_OFF, D_, R_ * 2 * D_, R_ * 2 * D_, S_, R_,
        (long)S_ * R_ * 2 * D_, 2 * D_, (long)S_ * R_ * 2 * D_, 2 * D_,
        (long)R_ * S_ * S_, (long)S_ * S_, mask, 0.0f, nullptr);

    (void)in_sizes; (void)n_in; (void)out_size; (void)ws_size;
}

// Round 7
// 252.628 us; speedup vs baseline: 1.0150x; 1.0150x over previous
//
#include <hip/hip_runtime.h>
#include <math.h>

#define H_   768
#define NH_  4
#define HD_  192
#define E_   9
#define R_   12
#define D_   64
#define B_   4
#define S_   1024
#define H3_  (3 * H_)
#define MBS_ (B_ * S_)

typedef unsigned short u16;
typedef __attribute__((ext_vector_type(4))) int   i32x4;
typedef __attribute__((ext_vector_type(4))) float f32x4;

static const long OUT_REL_OFF = (long)B_ * E_ * S_ * S_;                    // 37,748,736
static const long OUT_ENH_OFF = OUT_REL_OFF + (long)B_ * R_ * S_ * S_;      // 88,080,384

__device__ __forceinline__ u16 f2bf(float f) {
    unsigned u = __builtin_bit_cast(unsigned, f);
    return (u16)((u + 0x7fffu + ((u >> 16) & 1u)) >> 16);
}
__device__ __forceinline__ float bf2f(u16 h) {
    return __builtin_bit_cast(float, (unsigned)h << 16);
}
__device__ __forceinline__ void gload16(const u16* g, u16* l) {
    __builtin_amdgcn_global_load_lds(
        (__attribute__((address_space(1))) void*)g,
        (__attribute__((address_space(3))) void*)l, 16, 0, 0);
}
__device__ __forceinline__ void mfma_bf16(f32x4& acc, i32x4 a, i32x4 b) {
    asm volatile("v_mfma_f32_16x16x32_bf16 %0, %1, %2, %0"
                 : "+v"(acc) : "v"(a), "v"(b));
}

// ---------------------------------------------------------------------------
// bf16 MFMA GEMM, NT: C[m,n] = sum_k A[m,k]*B[n,k]. BMxBN tile, BK=64,
// 4 waves (2x2), wave tile (BM/2)x(BN/2), 16x16x32 MFMA. LDS XOR-swizzle
// (granule ^= row&7) with pre-swizzled global source. XCD-swizzled grid.
// PIPE=1: 2-buffer ring, counted vmcnt (never 0 mid-loop), raw barriers,
//         stage(t+2) issued right after reads of buf[t&1] complete.
// PIPE=0: single-stage (K=64 logits GEMMs only).
// EPI 0: +bias (OBF sel bf16/fp32 out)
// EPI 1: logits epilogue (mask/tril/*0.125), fp32 out
// EPI 3: EPI1 + per-row max partials -> aux[(z*S+gm)*16 + bx*2+wc]
// EPI 4: +bias then fused interleaved RoPE (pair via shfl_xor 1), bf16 out
// EPI 5: t=exp(v*scale) (0 if masked), bf16 out + row-sum partials -> aux
// EPI 6: v *= 1/rowsum (aux = psum in), bf16 out
// EPI 7: +bias, bf16 out, and V columns (gn>=1536) also written transposed
//        into vt=(u16*)aux as vt[((b*NH+h)*HD+d)*S + s]
// ---------------------------------------------------------------------------
template<int BM, int BN, int EPI, int OBF, int PIPE>
__global__ __launch_bounds__(256) void gemm_mfma(
    const u16* __restrict__ A, const u16* __restrict__ Bw,
    const float* __restrict__ bias, void* __restrict__ Cv,
    int K, int lda, int ldb, int ldc, int nh,
    long sAb, long sAh, long sBb, long sBh, long sCb, long sCh,
    const float* __restrict__ mask, float scale, float* __restrict__ aux)
{
    constexpr int MI = BM / 32, NJ = BN / 32;
    constexpr int BUFE = (BM + BN) * 64;            // u16 elems per stage buffer
    constexpr int LPS  = BM / 32 + BN / 32;         // gloads per thread per stage
    const int z = blockIdx.z;
    const int zb = z / nh, zh = z - zb * nh;
    A  += zb * sAb + zh * sAh;
    Bw += zb * sBb + zh * sBh;

    // XCD-aware bijective swizzle of (bx,by); all grids have nwg%8==0
    const int gx = gridDim.x, gy = gridDim.y;
    int id = blockIdx.y * gx + blockIdx.x;
    const int nwg = gx * gy;
    if ((nwg & 7) == 0) id = (id & 7) * (nwg >> 3) + (id >> 3);
    const int bx = id % gx, by = id / gx;
    const int m0 = by * BM, n0 = bx * BN;

    __shared__ u16 lds[(PIPE ? 2 : 1) * BUFE];

    const int t = threadIdx.x;
    const int lane = t & 63, wid = t >> 6;
    const int wr = wid >> 1, wc = wid & 1;
    const int l16 = lane & 15, l4 = lane >> 4;

    auto stage = [&](int kt, u16* la) {
        u16* lb = la + BM * 64;
        const int k0 = kt << 6;
        #pragma unroll
        for (int i = 0; i < BM / 32; ++i) {
            const int e = i * 256 + t;
            const int row = e >> 3;
            const int c = ((e & 7) ^ (row & 7)) << 3;      // pre-swizzled source
            gload16(A + (long)(m0 + row) * lda + k0 + c, la + e * 8);
        }
        #pragma unroll
        for (int i = 0; i < BN / 32; ++i) {
            const int e = i * 256 + t;
            const int row = e >> 3;
            const int c = ((e & 7) ^ (row & 7)) << 3;
            gload16(Bw + (long)(n0 + row) * ldb + k0 + c, lb + e * 8);
        }
    };

    f32x4 acc[MI][NJ];
    #pragma unroll
    for (int mi = 0; mi < MI; ++mi)
        #pragma unroll
        for (int nj = 0; nj < NJ; ++nj)
            #pragma unroll
            for (int q = 0; q < 4; ++q) acc[mi][nj][q] = 0.0f;

    const int nt = K >> 6;

    if (PIPE == 0) {
        stage(0, lds);
        __syncthreads();
        const u16* la = lds;
        const u16* lb = lds + BM * 64;
        i32x4 af[MI][2], bfr[NJ][2];
        #pragma unroll
        for (int mi = 0; mi < MI; ++mi)
            #pragma unroll
            for (int kk = 0; kk < 2; ++kk) {
                const int row = wr * (BM / 2) + mi * 16 + l16;
                af[mi][kk] = *(const i32x4*)&la[row * 64 + ((((kk << 2) + l4) ^ (row & 7)) << 3)];
            }
        #pragma unroll
        for (int nj = 0; nj < NJ; ++nj)
            #pragma unroll
            for (int kk = 0; kk < 2; ++kk) {
                const int row = wc * (BN / 2) + nj * 16 + l16;
                bfr[nj][kk] = *(const i32x4*)&lb[row * 64 + ((((kk << 2) + l4) ^ (row & 7)) << 3)];
            }
        #pragma unroll
        for (int kk = 0; kk < 2; ++kk)
            #pragma unroll
            for (int mi = 0; mi < MI; ++mi)
                #pragma unroll
                for (int nj = 0; nj < NJ; ++nj)
                    mfma_bf16(acc[mi][nj], af[mi][kk], bfr[nj][kk]);
    } else {
        stage(0, lds);
        if (nt > 1) stage(1, lds + BUFE);
        for (int tt = 0; tt < nt; ++tt) {
            if (tt + 1 < nt) {
                if constexpr (LPS == 8) asm volatile("s_waitcnt vmcnt(8)" ::: "memory");
                else if constexpr (LPS == 7) asm volatile("s_waitcnt vmcnt(7)" ::: "memory");
                else if constexpr (LPS == 6) asm volatile("s_waitcnt vmcnt(6)" ::: "memory");
                else asm volatile("s_waitcnt vmcnt(5)" ::: "memory");
            } else {
                asm volatile("s_waitcnt vmcnt(0)" ::: "memory");
            }
            __builtin_amdgcn_s_barrier();               // stage tt visible to all
            u16* la = lds + (tt & 1) * BUFE;
            const u16* lb = la + BM * 64;
            i32x4 af[MI][2], bfr[NJ][2];
            #pragma unroll
            for (int mi = 0; mi < MI; ++mi)
                #pragma unroll
                for (int kk = 0; kk < 2; ++kk) {
                    const int row = wr * (BM / 2) + mi * 16 + l16;
                    af[mi][kk] = *(const i32x4*)&la[row * 64 + ((((kk << 2) + l4) ^ (row & 7)) << 3)];
                }
            #pragma unroll
            for (int nj = 0; nj < NJ; ++nj)
                #pragma unroll
                for (int kk = 0; kk < 2; ++kk) {
                    const int row = wc * (BN / 2) + nj * 16 + l16;
                    bfr[nj][kk] = *(const i32x4*)&lb[row * 64 + ((((kk << 2) + l4) ^ (row & 7)) << 3)];
                }
            asm volatile("s_waitcnt lgkmcnt(0)" ::: "memory");
            __builtin_amdgcn_sched_barrier(0);
            __builtin_amdgcn_s_barrier();               // all waves done reading buf
            if (tt + 2 < nt) stage(tt + 2, la);         // overwrite just-read buffer
            #pragma unroll
            for (int kk = 0; kk < 2; ++kk)
                #pragma unroll
                for (int mi = 0; mi < MI; ++mi)
                    #pragma unroll
                    for (int nj = 0; nj < NJ; ++nj)
                        mfma_bf16(acc[mi][nj], af[mi][kk], bfr[nj][kk]);
        }
        __syncthreads();
    }
    __builtin_amdgcn_sched_barrier(0);
    asm volatile("s_nop 7");
    asm volatile("s_nop 7");
    __builtin_amdgcn_sched_barrier(0);

    if (EPI == 1 || EPI == 3 || EPI == 5) mask += (long)zb * S_;
    const long cbase = zb * sCb + zh * sCh;

    float* sminv = (float*)lds;   // EPI 6 only: reuse dead LDS after K-loop
    if (EPI == 6) {               // preload 1/rowsum from 16 partials per row
        if (t < BM) {
            const float* pp = aux + ((long)z * S_ + m0 + t) * 16;
            float s = 0.0f;
            #pragma unroll
            for (int i = 0; i < 16; ++i) s += pp[i];
            sminv[t] = 1.0f / s;
        }
        __syncthreads();
    }

    float red[MI][4];
    if (EPI == 3 || EPI == 5) {
        #pragma unroll
        for (int mi = 0; mi < MI; ++mi)
            #pragma unroll
            for (int r = 0; r < 4; ++r) red[mi][r] = (EPI == 3) ? -INFINITY : 0.0f;
    }

    #pragma unroll
    for (int mi = 0; mi < MI; ++mi) {
        #pragma unroll
        for (int nj = 0; nj < NJ; ++nj) {
            const int gn = n0 + wc * (BN / 2) + nj * 16 + l16;
            const float bv = ((EPI == 0 || EPI == 4 || EPI == 7) && bias) ? bias[gn] : 0.0f;
            float invf = 0.0f;
            if (EPI == 4) invf = exp2f(-(float)((gn & 63) >> 1) * 0.41524101186092503f);
            #pragma unroll
            for (int r = 0; r < 4; ++r) {
                const int gm = m0 + wr * (BM / 2) + mi * 16 + l4 * 4 + r;
                float v = acc[mi][nj][r];
                const long cidx = cbase + (long)gm * ldc + gn;
                if (EPI == 0) {
                    v += bv;
                    if (OBF) ((u16*)Cv)[cidx] = f2bf(v);
                    else     ((float*)Cv)[cidx] = v;
                } else if (EPI == 7) {
                    v += bv;
                    const u16 bfv = f2bf(v);
                    ((u16*)Cv)[cidx] = bfv;
                    if (gn >= 2 * H_) {
                        const int hh = (gn - 2 * H_) / HD_;
                        const int dd = (gn - 2 * H_) - hh * HD_;
                        const int bb = gm >> 10, ss = gm & (S_ - 1);
                        ((u16*)aux)[((long)(bb * NH_ + hh) * HD_ + dd) * S_ + ss] = bfv;
                    }
                } else if (EPI == 1 || EPI == 3) {
                    const float pad = mask[gn];
                    v = v * pad - (1.0f - pad) * 1e12f;
                    if (gm > gn) v -= 1e12f;
                    v *= 0.125f;
                    ((float*)Cv)[cidx] = v;
                    if (EPI == 3) red[mi][r] = fmaxf(red[mi][r], v);
                } else if (EPI == 5) {
                    float tv = 0.0f;
                    if (mask[gn] != 0.0f) tv = __expf(v * scale);
                    ((u16*)Cv)[cidx] = f2bf(tv);
                    red[mi][r] += tv;
                } else if (EPI == 6) {
                    v *= sminv[gm - m0];
                    ((u16*)Cv)[cidx] = f2bf(v);
                } else { // EPI == 4
                    v += bv;
                    const int sp = gm & (S_ - 1);
                    float sn, cs;
                    __sincosf((float)sp * invf, &sn, &cs);
                    const float pv = __shfl_xor(v, 1, 64);
                    v = (gn & 1) ? fmaf(v, cs, pv * sn) : fmaf(v, cs, -pv * sn);
                    ((u16*)Cv)[cidx] = f2bf(v);
                }
            }
        }
    }

    if (EPI == 3 || EPI == 5) {
        #pragma unroll
        for (int mi = 0; mi < MI; ++mi) {
            #pragma unroll
            for (int r = 0; r < 4; ++r) {
                float m = red[mi][r];
                if (EPI == 3) {
                    m = fmaxf(m, __shfl_xor(m, 1, 64));
                    m = fmaxf(m, __shfl_xor(m, 2, 64));
                    m = fmaxf(m, __shfl_xor(m, 4, 64));
                    m = fmaxf(m, __shfl_xor(m, 8, 64));
                } else {
                    m += __shfl_xor(m, 1, 64);
                    m += __shfl_xor(m, 2, 64);
                    m += __shfl_xor(m, 4, 64);
                    m += __shfl_xor(m, 8, 64);
                }
                if (l16 == 0) {
                    const int gm = m0 + wr * (BM / 2) + mi * 16 + l4 * 4 + r;
                    aux[((long)z * S_ + gm) * 16 + bx * 2 + wc] = m;
                }
            }
        }
    }
}

// ---------------------------------------------------------------------------
// Fused fp32->bf16 cast of hs + 5 weight matrices. 1024 elems per block.
// ---------------------------------------------------------------------------
__global__ __launch_bounds__(256) void cast_all(
    const float* __restrict__ hs, const float* __restrict__ ipw,
    const float* __restrict__ opw, const float* __restrict__ gw,
    const float* __restrict__ entw, const float* __restrict__ relw,
    u16* hs_o, u16* ipw_o, u16* opw_o, u16* gw_o, u16* entw_o, u16* relw_o)
{
    const int blk = blockIdx.x;
    const float* in; u16* out; long base;
    if      (blk < 3072) { in = hs;   out = hs_o;   base = (long)blk * 1024; }
    else if (blk < 4800) { in = ipw;  out = ipw_o;  base = (long)(blk - 3072) * 1024; }
    else if (blk < 5376) { in = opw;  out = opw_o;  base = (long)(blk - 4800) * 1024; }
    else if (blk < 5952) { in = gw;   out = gw_o;   base = (long)(blk - 5376) * 1024; }
    else if (blk < 6816) { in = entw; out = entw_o; base = (long)(blk - 5952) * 1024; }
    else                 { in = relw; out = relw_o; base = (long)(blk - 6816) * 1024; }
    const long idx = base + (long)threadIdx.x * 4;
    const float4 v = *(const float4*)&in[idx];
    ushort4 o; o.x = f2bf(v.x); o.y = f2bf(v.y); o.z = f2bf(v.z); o.w = f2bf(v.w);
    *(ushort4*)&out[idx] = o;
}

// ---------------------------------------------------------------------------
// x = hs + sigmoid(gl)*ao ; LayerNorm -> enh fp32 (d_out) + relh[:768] bf16
// ao/gl packed in aogl rows of 1536: [0..768) = ao, [768..1536) = gl.
// ---------------------------------------------------------------------------
__global__ __launch_bounds__(256) void gate_ln_bf(
    const float* __restrict__ hs, const u16* __restrict__ aogl,
    const float* __restrict__ g, const float* __restrict__ bta,
    float* __restrict__ enh, u16* __restrict__ relh)
{
    const long row = blockIdx.x;
    const float* hrow = hs + row * H_;
    const u16* arow = aogl + row * (2 * H_);
    const int tid = threadIdx.x;
    float x[3];
    float sum = 0.0f, sq = 0.0f;
    #pragma unroll
    for (int i = 0; i < 3; ++i) {
        const int j = tid + i * 256;
        const float a = bf2f(arow[j]);
        const float gt = 1.0f / (1.0f + __expf(-bf2f(arow[H_ + j])));
        const float xv = hrow[j] + gt * a;
        x[i] = xv; sum += xv; sq += xv * xv;
    }
    __shared__ float sm[8];
    #pragma unroll
    for (int o = 32; o > 0; o >>= 1) {
        sum += __shfl_xor(sum, o, 64);
        sq  += __shfl_xor(sq, o, 64);
    }
    const int lane = tid & 63, wid = tid >> 6;
    if (lane == 0) { sm[wid] = sum; sm[4 + wid] = sq; }
    __syncthreads();
    sum = sm[0] + sm[1] + sm[2] + sm[3];
    sq  = sm[4] + sm[5] + sm[6] + sm[7];
    const float mu = sum * (1.0f / (float)H_);
    float var = sq * (1.0f / (float)H_) - mu * mu;
    var = fmaxf(var, 0.0f);
    const float inv = 1.0f / sqrtf(var + 1e-5f);
    #pragma unroll
    for (int i = 0; i < 3; ++i) {
        const int j = tid + i * 256;
        const float o = (x[i] - mu) * inv * g[j] + bta[j];
        enh[row * H_ + j] = o;
        relh[row * (2 * H_) + j] = f2bf(o);
    }
}

// ---------------------------------------------------------------------------
// Fused: prior[t] = max over 16 partials; relh[:,768:] = relu(prior@pw^T+pb)
// One block per (b,m) row.
// ---------------------------------------------------------------------------
__global__ __launch_bounds__(256) void prior_fused(
    const float* __restrict__ pmax, const float* __restrict__ pw,
    const float* __restrict__ pb, u16* __restrict__ relh)
{
    const int row = blockIdx.x;               // b*S + m
    const int b = row >> 10, m = row & (S_ - 1);
    __shared__ float pr[E_];
    const int tid = threadIdx.x;
    if (tid < E_) {
        const float* pp = pmax + ((long)(b * E_ + tid) * S_ + m) * 16;
        float mx = -INFINITY;
        #pragma unroll
        for (int i = 0; i < 16; ++i) mx = fmaxf(mx, pp[i]);
        pr[tid] = mx;
    }
    __syncthreads();
    float p[E_];
    #pragma unroll
    for (int e = 0; e < E_; ++e) p[e] = pr[e];
    u16* orow = relh + (long)row * (2 * H_) + H_;
    #pragma unroll
    for (int i = 0; i < 3; ++i) {
        const int j = tid + i * 256;
        float a = pb[j];
        #pragma unroll
        for (int e = 0; e < E_; ++e) a = fmaf(p[e], pw[j * E_ + e], a);
        orow[j] = f2bf(fmaxf(a, 0.0f));
    }
}

// ---------------------------------------------------------------------------
extern "C" void kernel_launch(void* const* d_in, const int* in_sizes, int n_in,
                              void* d_out, int out_size, void* d_ws, size_t ws_size,
                              hipStream_t stream)
{
    const float* hs   = (const float*)d_in[0];
    const float* mask = (const float*)d_in[1];
    const float* ipw  = (const float*)d_in[2];
    const float* ipb  = (const float*)d_in[3];
    const float* opb  = (const float*)d_in[5];
    const float* gb   = (const float*)d_in[7];
    const float* lng  = (const float*)d_in[8];
    const float* lnb  = (const float*)d_in[9];
    const float* entw = (const float*)d_in[10];
    const float* entb = (const float*)d_in[11];
    const float* prw  = (const float*)d_in[12];
    const float* prb  = (const float*)d_in[13];
    const float* relw = (const float*)d_in[14];
    const float* relb = (const float*)d_in[15];
    const float* opw  = (const float*)d_in[4];
    const float* gw   = (const float*)d_in[6];
    float* out = (float*)d_out;
    char* base = (char*)d_ws;

    // ws layout (bytes)
    u16* ipw_bf  = (u16*)(base + 0);          // 3,538,944
    u16* opw_bf  = (u16*)(base + 3538944);    // 1,179,648  } contiguous pair ->
    u16* gw_bf   = (u16*)(base + 4718592);    // 1,179,648  } combined [1536][768]
    u16* entw_bf = (u16*)(base + 5898240);    // 1,769,472
    u16* relw_bf = (u16*)(base + 7667712);    // 4,718,592
    u16* hs_bf   = (u16*)(base + 12386304);   // 6,291,456  [dead after qkv]
    u16* qkv_bf  = (u16*)(base + 18677760);   // 18,874,368 [dead after scores]
    u16* vt_bf   = (u16*)(base + 37552128);   // 6,291,456  [dead after PV]
    u16* sc_bf   = (u16*)(base + 43843584);   // 33,554,432 [dead after PV]
    u16* ctx_bf  = (u16*)(base + 77398016);   // 6,291,456
    u16* aogl_bf = (u16*)(base + 83689472);   // 12,582,912
    float* bias2 = (float*)(base + 96272384); //      6,144 (opb|gb)
    float* psum  = (float*)(base + 96280576); //  1,048,576
    float* pmax  = (float*)(base + 97329152); //  2,359,296
    u16* relh_bf = (u16*)(base + 18677760);   // 12,582,912 (reuse qkv region)
    u16* projr   = (u16*)(base + 37552128);   // 12,582,912 (reuse vt+sc region)
    float* enh   = out + OUT_ENH_OFF;

    const float qscale = 0.07216878364870323f; // 1/sqrt(192)

    // combined out_proj|gate bias
    hipMemcpyAsync(bias2, opb, H_ * sizeof(float), hipMemcpyDeviceToDevice, stream);
    hipMemcpyAsync(bias2 + H_, gb, H_ * sizeof(float), hipMemcpyDeviceToDevice, stream);

    // 0. casts
    cast_all<<<9120, 256, 0, stream>>>(hs, ipw, opw, gw, entw, relw,
                                       hs_bf, ipw_bf, opw_bf, gw_bf, entw_bf, relw_bf);

    // 1. qkv = hs @ in_proj_w.T + b (4096 x 2304, K=768) + fused V-transpose
    gemm_mfma<128,96,7,1,1><<<dim3(24, 32, 1), 256, 0, stream>>>(
        hs_bf, ipw_bf, ipb, qkv_bf, H_, H_, H_, H3_, 1,
        0,0,0,0,0,0, nullptr, 0.0f, (float*)vt_bf);

    // 2. scores: t = exp(QK^T/sqrt(HD)) (masked->0), bf16 + row-sum partials
    gemm_mfma<128,128,5,1,1><<<dim3(8, 8, B_ * NH_), 256, 0, stream>>>(
        qkv_bf, qkv_bf + H_, nullptr, sc_bf, HD_, H3_, H3_, S_, NH_,
        (long)S_ * H3_, HD_, (long)S_ * H3_, HD_,
        (long)NH_ * S_ * S_, (long)S_ * S_, mask, qscale, psum);

    // 3. ctx = (T @ V) / rowsum   (16 x 1024 x 192, K=1024)
    gemm_mfma<64,96,6,1,1><<<dim3(2, 16, B_ * NH_), 256, 0, stream>>>(
        sc_bf, vt_bf, nullptr, ctx_bf, S_, S_, S_, H_, NH_,
        (long)NH_ * S_ * S_, (long)S_ * S_, (long)NH_ * HD_ * S_, (long)HD_ * S_,
        (long)S_ * H_, HD_, nullptr, 0.0f, psum);

    // 4. [attn_out | gate_lin] = ctx @ [opw|gw]^T + [opb|gb]  (4096 x 1536, K=768)
    gemm_mfma<128,96,0,1,1><<<dim3(16, 32, 1), 256, 0, stream>>>(
        ctx_bf, opw_bf, bias2, aogl_bf, H_, H_, H_, 2 * H_, 1,
        0,0,0,0,0,0, nullptr, 0.0f, nullptr);

    // 5. enhanced = LN(hs + sigmoid(gl)*ao) -> enh fp32 + relh[:768]
    gate_ln_bf<<<MBS_, 256, 0, stream>>>(hs, aogl_bf, lng, lnb, enh, relh_bf);

    // 6. ent projection + fused RoPE (4096 x 1152, K=768) -> projr bf16
    gemm_mfma<64,96,4,1,1><<<dim3(12, 64, 1), 256, 0, stream>>>(
        relh_bf, entw_bf, entb, projr, H_, 2 * H_, H_, E_ * 2 * D_, 1,
        0,0,0,0,0,0, nullptr, 0.0f, nullptr);

    // 7. ent logits + fused rowmax partials -> out[0], pmax   (K=64)
    gemm_mfma<128,128,3,0,0><<<dim3(8, 8, B_ * E_), 256, 0, stream>>>(
        projr, projr + D_, nullptr, out, D_, E_ * 2 * D_, E_ * 2 * D_, S_, E_,
        (long)S_ * E_ * 2 * D_, 2 * D_, (long)S_ * E_ * 2 * D_, 2 * D_,
        (long)E_ * S_ * S_, (long)S_ * S_, mask, 0.0f, pmax);

    // 8. prior reduce + feat -> relh[:, 768:]
    prior_fused<<<MBS_, 256, 0, stream>>>(pmax, prw, prb, relh_bf);

    // 9. rel projection + fused RoPE (4096 x 1536, K=1536) -> projr bf16
    gemm_mfma<128,96,4,1,1><<<dim3(16, 32, 1), 256, 0, stream>>>(
        relh_bf, relw_bf, relb, projr, 2 * H_, 2 * H_, 2 * H_, R_ * 2 * D_, 1,
        0,0,0,0,0,0, nullptr, 0.0f, nullptr);

    // 10. rel logits -> out[1]   (48 x 1024 x 1024, K=64)
    gemm_mfma<128,128,1,0,0><<<dim3(8, 8, B_ * R_), 256, 0, stream>>>(
        projr, projr + D_, nullptr, out + OUT_REL_OFF, D_, R_ * 2 * D_, R_ * 2 * D_, S_, R_,
        (long)S_ * R_ * 2 * D_, 2 * D_, (long)S_ * R_ * 2 * D_, 2 * D_,
        (long)R_ * S_ * S_, (long)S_ * S_, mask, 0.0f, nullptr);

    (void)in_sizes; (void)n_in; (void)out_size; (void)ws_size;
}